// Round 3
// baseline (716.358 us; speedup 1.0000x reference)
//
#include <hip/hip_runtime.h>
#include <stdint.h>

typedef unsigned short u16;
typedef __attribute__((ext_vector_type(8))) short bf16x8;
typedef __attribute__((ext_vector_type(4))) float f32x4;
typedef __attribute__((ext_vector_type(8))) u16 u16x8;
typedef __attribute__((ext_vector_type(4))) u16 u16x4;

static constexpr int kS = 8192;    // B*L tokens
static constexpr int kH = 1024;
static constexpr int kE = 8;
static constexpr int kI = 4096;
static constexpr int kCap = 2048;  // capacity per expert

__device__ __forceinline__ u16 f2b(float f) {
  unsigned u = __float_as_uint(f);
  u += 0x7FFF + ((u >> 16) & 1);   // RNE
  return (u16)(u >> 16);
}
__device__ __forceinline__ float b2f(u16 v) { return __uint_as_float(((unsigned)v) << 16); }

// async global->LDS, 16B per lane; LDS dest = wave-uniform base + lane*16
__device__ __forceinline__ void gll16(const void* g, void* l) {
  __builtin_amdgcn_global_load_lds((const __attribute__((address_space(1))) void*)g,
                                   (__attribute__((address_space(3))) void*)l, 16, 0, 0);
}

// ---------------- init ----------------
__global__ void k_init(int* counts) {
  int i = threadIdx.x;
  if (i < kE) counts[i] = 0;
}

// ---------------- LN + gate + route (one block per token), fp32 I/O ----------------
__global__ __launch_bounds__(256) void k_ln_route(
    const float* __restrict__ x, const float* __restrict__ gw,
    const float* __restrict__ gamma, const float* __restrict__ beta,
    u16* __restrict__ xn, int* __restrict__ top1A, int* __restrict__ slotA,
    float* __restrict__ wtokA, int* __restrict__ counts, float* __restrict__ dout) {
  const int tkn = blockIdx.x;
  const int tid = threadIdx.x;
  const int w = tid >> 6, l = tid & 63;
  const float* row = x + (size_t)tkn * kH;
  f32x4 v = *(const f32x4*)(row + tid * 4);
  float s = v[0] + v[1] + v[2] + v[3];
  float ss = v[0] * v[0] + v[1] * v[1] + v[2] * v[2] + v[3] * v[3];
#pragma unroll
  for (int o = 32; o > 0; o >>= 1) { s += __shfl_down(s, o); ss += __shfl_down(ss, o); }
  __shared__ float red[8];
  __shared__ float bc[2];
  __shared__ float red2[4][8];
  __shared__ int skeep;
  if (l == 0) { red[w] = s; red[4 + w] = ss; }
  __syncthreads();
  if (tid == 0) {
    float S1 = red[0] + red[1] + red[2] + red[3];
    float S2 = red[4] + red[5] + red[6] + red[7];
    float mean = S1 * (1.0f / kH);
    float var = S2 * (1.0f / kH) - mean * mean;
    bc[0] = mean;
    bc[1] = 1.0f / sqrtf(var + 1e-5f);
  }
  __syncthreads();
  float mean = bc[0], rstd = bc[1];
  f32x4 gv = *(const f32x4*)(gamma + tid * 4);
  f32x4 bv = *(const f32x4*)(beta + tid * 4);
  float xh[4];
  u16x4 xo;
#pragma unroll
  for (int i = 0; i < 4; ++i) {
    xh[i] = (v[i] - mean) * rstd * gv[i] + bv[i];
    xo[i] = f2b(xh[i]);
  }
  *(u16x4*)(xn + (size_t)tkn * kH + tid * 4) = xo;
  // gate logits (8 experts), fp32 products + tree sums (matches fp32 np ref ~1e-6)
  float pe[8];
#pragma unroll
  for (int e = 0; e < 8; ++e) {
    f32x4 g4 = *(const f32x4*)(gw + e * kH + tid * 4);
    pe[e] = xh[0] * g4[0] + xh[1] * g4[1] + xh[2] * g4[2] + xh[3] * g4[3];
  }
#pragma unroll
  for (int o = 32; o > 0; o >>= 1) {
#pragma unroll
    for (int e = 0; e < 8; ++e) pe[e] += __shfl_down(pe[e], o);
  }
  if (l == 0) {
#pragma unroll
    for (int e = 0; e < 8; ++e) red2[w][e] = pe[e];
  }
  __syncthreads();
  if (tid == 0) {
    double L[8];
    for (int e = 0; e < 8; ++e)
      L[e] = (double)red2[0][e] + (double)red2[1][e] + (double)red2[2][e] + (double)red2[3][e];
    int am = 0;
    double mx = L[0];
    for (int e = 1; e < 8; ++e)
      if (L[e] > mx) { mx = L[e]; am = e; }     // first-max, matches jnp.argmax
    double den = 0.0;
    for (int e = 0; e < 8; ++e) den += exp(L[e] - mx);
    int slot = atomicAdd(&counts[am], 1);
    int keep = slot < kCap;
    top1A[tkn] = am;
    slotA[tkn] = slot;
    wtokA[tkn] = keep ? (float)(1.0 / den) : 0.0f;
    skeep = keep;
  }
  __syncthreads();
  if (!skeep) *(f32x4*)(dout + (size_t)tkn * kH + tid * 4) = v;  // dropped: out = residual
}

// ---------------- offsets (tiny) ----------------
__global__ void k_offsets(const int* __restrict__ counts, int* __restrict__ off,
                          int* __restrict__ cntcap) {
  if (threadIdx.x == 0 && blockIdx.x == 0) {
    int acc = 0;
    for (int e = 0; e < kE; ++e) {
      off[e] = acc;
      int c = counts[e];
      if (c > kCap) c = kCap;
      if (c < 0) c = 0;
      cntcap[e] = c;
      acc += c;
    }
    off[kE] = acc;
  }
}

// ---------------- scatter token ids into per-expert compact rows ----------------
__global__ __launch_bounds__(256) void k_scatter(
    const int* __restrict__ top1A, const int* __restrict__ slotA,
    const float* __restrict__ wtokA, const int* __restrict__ off,
    int* __restrict__ idxs, float* __restrict__ wrow) {
  int i = blockIdx.x * 256 + threadIdx.x;
  if (i >= kS) return;
  int sl = slotA[i];
  if (sl < kCap) {
    int r = off[top1A[i]] + sl;
    idxs[r] = i;
    wrow[r] = wtokA[i];
  }
}

// ---------------- grouped NN GEMM, 128x128 tile, BK=64, 16x16x32 bf16 MFMA ----------------
// A: [rows][KDIM] bf16 (ws buffer), gathered (MODE 0) or compact (MODE 1), K contiguous.
// Bn: natural fp32 weights [e][KDIM][NDIM] (N fast) — cvt to bf16 + transpose into LDS.
// MODE 0: T1[g,:] = gelu(xn[idxs[g],:] @ wi[e])           (bf16 out to ws)
// MODE 1: out[tok,:] = x[tok,:] + wrow[g]*(T1[g,:] @ wo[e])  (fp32 out)
template <int KDIM, int NDIM, int MODE>
__global__ __launch_bounds__(256, 2) void k_gemm(
    const u16* __restrict__ A, const float* __restrict__ Bn, void* __restrict__ CoutV,
    const float* __restrict__ resid, const int* __restrict__ idxs,
    const float* __restrict__ wrow, const int* __restrict__ off,
    const int* __restrict__ cntcap) {
  __shared__ __align__(1024) char smem[32768];
  const int bx = blockIdx.x, by = blockIdx.y;
  const int e = by >> 4, t = by & 15;
  const int cnt = cntcap[e];
  const int rstart = t << 7;
  if (rstart >= cnt) return;
  const int base = off[e];
  const int tid = threadIdx.x;
  const int w = tid >> 6, l = tid & 63;
  const int mu = l & 7, ch = l >> 3;
  const int lm = l & 15, q = l >> 4;
  const int wm = w & 1, wn = w >> 1;

  // ---- A staging addresses (global_load_lds, 16B/lane, bf16 rows) ----
  const char* Ab = (const char*)A;
  size_t arow[4];
#pragma unroll
  for (int j = 0; j < 4; ++j) {
    int grp = w * 4 + j;
    int r = rstart + grp * 8 + mu;
    int rc = (r < cnt) ? r : (cnt - 1);   // clamp tail rows (stores are guarded)
    int g = base + rc;
    int src = (MODE == 0) ? idxs[g] : g;
    if (src < 0) src = 0;
    if (src >= kS) src = kS - 1;          // defensive: never read OOB
    arow[j] = (size_t)src * (KDIM * 2) + ch * 16;
  }

  // ---- B staging setup (fp32 load -> bf16 cvt -> transpose into LDS) ----
  const int cB = tid & 15;   // n-chunk (8 n each) within the 128-wide tile
  const int kp = tid >> 4;   // 0..15
  const int c7 = cB & 7;
  const float* Bsrc = Bn + (size_t)e * KDIM * NDIM + (size_t)bx * 128 + cB * 8;
  const float* bp[2];
  int ldsB[2];
#pragma unroll
  for (int it = 0; it < 2; ++it) {
    int kr0 = kp * 2 + it * 32;                 // even k row within BK=64
    bp[it] = Bsrc + (size_t)kr0 * NDIM;
    // LDS byte addr for (n = cB*8 + j, k = kr0): group cB, kchunk kr0>>3,
    // slot (j ^ (cB&7)) [XOR swizzle -> 2-way banks], byte (kr0&7)*2.
    ldsB[it] = 16384 + cB * 1024 + ((kr0 >> 3) << 7) + ((kr0 & 7) << 1) + (c7 << 4);
  }

  // ---- fragment read offsets ----
  const int l7 = lm & 7, lh = lm >> 3;
  int aoff[4], boff[4];
#pragma unroll
  for (int tt = 0; tt < 4; ++tt) {
    int m = wm * 64 + tt * 16 + lm;
    aoff[tt] = ((m >> 3) << 10) + ((m & 7) << 4) + (q << 7);
    int ng = wn * 8 + tt * 2 + lh;              // n>>3 for n = wn*64 + tt*16 + lm
    int slot = l7 ^ (tt * 2 + lh);              // (n&7) ^ ((n>>3)&7)
    boff[tt] = 16384 + (ng << 10) + (slot << 4) + (q << 7);
  }

  f32x4 acc[4][4];
#pragma unroll
  for (int a1 = 0; a1 < 4; ++a1)
#pragma unroll
    for (int a2 = 0; a2 < 4; ++a2) acc[a1][a2] = f32x4{0.f, 0.f, 0.f, 0.f};

  for (int kk = 0; kk < KDIM / 64; ++kk) {
    // A tile: 128 rows x 64k via global_load_lds (1KB per 8-row group)
#pragma unroll
    for (int j = 0; j < 4; ++j) {
      int grp = w * 4 + j;
      gll16(Ab + arow[j], smem + grp * 1024);
      arow[j] += 128;
    }
    // B tile: 2x (2 fp32 rows x 8 n), cvt bf16, pack k/k+1 pairs, scatter into LDS
#pragma unroll
    for (int it = 0; it < 2; ++it) {
      f32x4 r0a = *(const f32x4*)(bp[it]);
      f32x4 r0b = *(const f32x4*)(bp[it] + 4);
      f32x4 r1a = *(const f32x4*)(bp[it] + NDIM);
      f32x4 r1b = *(const f32x4*)(bp[it] + NDIM + 4);
      bp[it] += 64 * NDIM;
#pragma unroll
      for (int j = 0; j < 4; ++j) {
        unsigned pk = (unsigned)f2b(r0a[j]) | ((unsigned)f2b(r1a[j]) << 16);
        *(unsigned*)(smem + (ldsB[it] ^ (j << 4))) = pk;
      }
#pragma unroll
      for (int j = 0; j < 4; ++j) {
        unsigned pk = (unsigned)f2b(r0b[j]) | ((unsigned)f2b(r1b[j]) << 16);
        *(unsigned*)(smem + (ldsB[it] ^ ((j + 4) << 4))) = pk;
      }
    }
    __syncthreads();
#pragma unroll
    for (int s2 = 0; s2 < 2; ++s2) {
      bf16x8 af[4], bfr[4];
#pragma unroll
      for (int tm = 0; tm < 4; ++tm) af[tm] = *(const bf16x8*)(smem + aoff[tm] + s2 * 512);
#pragma unroll
      for (int tn = 0; tn < 4; ++tn) bfr[tn] = *(const bf16x8*)(smem + boff[tn] + s2 * 512);
#pragma unroll
      for (int tm = 0; tm < 4; ++tm)
#pragma unroll
        for (int tn = 0; tn < 4; ++tn)
          acc[tm][tn] = __builtin_amdgcn_mfma_f32_16x16x32_bf16(af[tm], bfr[tn], acc[tm][tn], 0, 0, 0);
    }
    __syncthreads();
  }

  // epilogue: per-wave LDS transpose of C fragments -> vectorized row stores
  char* eb = smem + w * 8192;
  float* ebf = (float*)eb;
  const int row16 = l >> 2, q2 = l & 3;
#pragma unroll
  for (int tm = 0; tm < 4; ++tm) {
#pragma unroll
    for (int tn = 0; tn < 4; ++tn) {
#pragma unroll
      for (int r = 0; r < 4; ++r) {
        float vv = acc[tm][tn][r];
        if (MODE == 0) vv = 0.5f * vv * (1.0f + erff(vv * 0.707106781186547524f));
        ebf[(q * 4 + r) * 68 + tn * 16 + lm] = vv;
      }
    }
    asm volatile("s_waitcnt lgkmcnt(0)" ::: "memory");
    int rl = rstart + wm * 64 + tm * 16 + row16;
#pragma unroll
    for (int p = 0; p < 2; ++p) {
      int chn = q2 * 2 + p;
      f32x4 v0 = *(const f32x4*)(eb + (row16 * 68 + chn * 8) * 4);
      f32x4 v1 = *(const f32x4*)(eb + (row16 * 68 + chn * 8 + 4) * 4);
      if (rl < cnt) {
        int g = base + rl;
        int col = bx * 128 + wn * 64 + chn * 8;
        if (MODE == 0) {
          u16* OutT = (u16*)CoutV;
          u16x8 ov;
#pragma unroll
          for (int i2 = 0; i2 < 4; ++i2) { ov[i2] = f2b(v0[i2]); ov[4 + i2] = f2b(v1[i2]); }
          *(u16x8*)(OutT + (size_t)g * NDIM + col) = ov;
        } else {
          float* OutF = (float*)CoutV;
          int tok = idxs[g];
          if (tok < 0) tok = 0;
          if (tok >= kS) tok = kS - 1;
          float wv = wrow[g];
          const float* rp = resid + (size_t)tok * NDIM + col;
          f32x4 r0 = *(const f32x4*)(rp);
          f32x4 r1 = *(const f32x4*)(rp + 4);
          f32x4 o0, o1;
#pragma unroll
          for (int i2 = 0; i2 < 4; ++i2) {
            o0[i2] = r0[i2] + wv * v0[i2];
            o1[i2] = r1[i2] + wv * v1[i2];
          }
          *(f32x4*)(OutF + (size_t)tok * NDIM + col) = o0;
          *(f32x4*)(OutF + (size_t)tok * NDIM + col + 4) = o1;
        }
      }
    }
    asm volatile("s_waitcnt lgkmcnt(0)" ::: "memory");
  }
}

extern "C" void kernel_launch(void* const* d_in, const int* in_sizes, int n_in,
                              void* d_out, int out_size, void* d_ws, size_t ws_size,
                              hipStream_t stream) {
  const float* x     = (const float*)d_in[0];
  const float* gw    = (const float*)d_in[1];
  const float* gamma = (const float*)d_in[2];
  const float* beta  = (const float*)d_in[3];
  const float* wi    = (const float*)d_in[4];
  const float* wo    = (const float*)d_in[5];
  float* out = (float*)d_out;
  char* ws = (char*)d_ws;
  (void)in_sizes; (void)n_in; (void)out_size; (void)ws_size;

  size_t o = 0;
  auto alloc = [&](size_t b) -> void* {
    void* p = ws + o;
    o = (o + b + 255) & ~(size_t)255;
    return p;
  };
  u16* xn    = (u16*)alloc((size_t)kS * kH * 2);       // 16.8 MB normalized tokens (bf16)
  u16* T1    = (u16*)alloc((size_t)kS * kI * 2);       // 67.1 MB hidden gelu (bf16)
  int* idxs  = (int*)alloc(kS * 4);
  float* wrow = (float*)alloc(kS * 4);
  int* top1A = (int*)alloc(kS * 4);
  int* slotA = (int*)alloc(kS * 4);
  float* wtokA = (float*)alloc(kS * 4);
  int* counts = (int*)alloc(64);
  int* off    = (int*)alloc(64);
  int* cntcap = (int*)alloc(64);
  // total ws use: ~84.1 MB

  hipLaunchKernelGGL(k_init, dim3(1), dim3(64), 0, stream, counts);
  hipLaunchKernelGGL(k_ln_route, dim3(kS), dim3(256), 0, stream,
                     x, gw, gamma, beta, xn, top1A, slotA, wtokA, counts, out);
  hipLaunchKernelGGL(k_offsets, dim3(1), dim3(1), 0, stream, counts, off, cntcap);
  hipLaunchKernelGGL(k_scatter, dim3(kS / 256), dim3(256), 0, stream,
                     top1A, slotA, wtokA, off, idxs, wrow);
  hipLaunchKernelGGL((k_gemm<kH, kI, 0>), dim3(kI / 128, 128), dim3(256), 0, stream,
                     xn, wi, (void*)T1, (const float*)nullptr, idxs, wrow, off, cntcap);
  hipLaunchKernelGGL((k_gemm<kI, kH, 1>), dim3(kH / 128, 128), dim3(256), 0, stream,
                     T1, wo, (void*)out, x, idxs, wrow, off, cntcap);
}